// Round 1
// baseline (517.263 us; speedup 1.0000x reference)
//
#include <hip/hip_runtime.h>
#include <math.h>

#define ALPHA 0.2f
#define BN_EPS 1e-5f
#define NEG_INF -9e15f
#define NN 4096
#define FF 64
#define BB 4
#define INV_DK (1.0f/64.0f)

// ---------------------------------------------------------------------------
// Kernel 1: Wh = h @ W  (per-row), Wh1 = Wh @ a[:64], Wh2 = Wh @ a[64:]
// rows = B*N = 16384. 256 thr = 4 waves, 2 rows/wave -> 8 rows/block.
// ---------------------------------------------------------------------------
__global__ __launch_bounds__(256)
void k_wh(const float* __restrict__ h, const float* __restrict__ W,
          const float* __restrict__ a, float* __restrict__ Wh,
          float* __restrict__ Wh1, float* __restrict__ Wh2) {
  __shared__ float sW[64 * 64];
  int t = threadIdx.x;
#pragma unroll
  for (int i = 0; i < 16; ++i) sW[i * 256 + t] = W[i * 256 + t];
  __syncthreads();
  int wv = t >> 6, lane = t & 63;
  float a1 = a[lane], a2 = a[64 + lane];
  int row0 = blockIdx.x * 8 + wv * 2;
  for (int r = 0; r < 2; ++r) {
    int row = row0 + r;                       // row in [0, B*N)
    const float* hr = h + (size_t)row * 64;
    float acc = 0.f;
#pragma unroll
    for (int k = 0; k < 64; ++k) acc = fmaf(hr[k], sW[k * 64 + lane], acc);
    Wh[(size_t)row * 64 + lane] = acc;
    float r1 = acc * a1, r2 = acc * a2;
#pragma unroll
    for (int s = 32; s; s >>= 1) { r1 += __shfl_xor(r1, s); r2 += __shfl_xor(r2, s); }
    if (lane == 0) { Wh1[row] = r1; Wh2[row] = r2; }
  }
}

// ---------------------------------------------------------------------------
// Kernel 2: masked-softmax attention aggregate + fused BN + residual + ELU.
// 512 threads = 8 waves. wave w: batch b = w>>1, row-half ih = w&1.
// Block owns 8 node rows (all 4 batches): gi = blockIdx.x*8 + ih*4 + i.
// Softmax uses m=0 (scores are O(0.3); shift-invariant; masked -> exp(-9e15)=0).
// ---------------------------------------------------------------------------
__global__ __launch_bounds__(512)
void k_gat(const float* __restrict__ h, const int* __restrict__ adj,
           const float* __restrict__ gamma, const float* __restrict__ beta,
           const float* __restrict__ Wh, const float* __restrict__ Wh1,
           const float* __restrict__ Wh2, float* __restrict__ out) {
  __shared__ float P[8][4][68];     // per-wave p tile [i][j-lane], padded
  __shared__ float part[8][4][2];   // per-wave BN partials [i][{sum,sumsq}]
  int t = threadIdx.x;
  int w = t >> 6, lane = t & 63;
  int b = w >> 1, ih = w & 1;
  int gi0 = blockIdx.x * 8 + ih * 4;
  const float* wh2 = Wh2 + b * NN;
  const float* whb = Wh + (size_t)b * NN * FF;

  float w1[4];
#pragma unroll
  for (int i = 0; i < 4; ++i) w1[i] = Wh1[b * NN + gi0 + i];

  float lsum[4] = {0.f, 0.f, 0.f, 0.f};
  float acc[4]  = {0.f, 0.f, 0.f, 0.f};
  const int il = lane & 3;          // which of the wave's 4 rows (accum role)
  const int fb = (lane >> 2) * 4;   // f-slice base (accum role)

  for (int jt = 0; jt < NN / 64; ++jt) {
    int j = jt * 64 + lane;
    float e2 = wh2[j];
#pragma unroll
    for (int i = 0; i < 4; ++i) {
      int av = adj[(size_t)(gi0 + i) * NN + j];
      float s = (w1[i] + e2) * INV_DK;
      s = s > 0.f ? s : ALPHA * s;            // LeakyReLU
      s = av > 0 ? s : NEG_INF;               // mask
      float pv = __expf(s);                   // masked -> 0 exactly
      lsum[i] += pv;
      P[w][i][lane] = pv;
    }
    __syncthreads();
    const float* wrow = whb + (size_t)(jt * 64) * FF + fb;
#pragma unroll 8
    for (int jj = 0; jj < 64; ++jj) {
      float4 v = *(const float4*)(wrow + (size_t)jj * FF);
      float pv = P[w][il][jj];
      acc[0] = fmaf(pv, v.x, acc[0]);
      acc[1] = fmaf(pv, v.y, acc[1]);
      acc[2] = fmaf(pv, v.z, acc[2]);
      acc[3] = fmaf(pv, v.w, acc[3]);
    }
    __syncthreads();
  }

  // softmax denominator: reduce lsum[i] across all 64 lanes
#pragma unroll
  for (int i = 0; i < 4; ++i) {
    float v = lsum[i];
#pragma unroll
    for (int s = 32; s; s >>= 1) v += __shfl_xor(v, s);
    lsum[i] = v;
  }
  float invl = 1.0f / lsum[il];
#pragma unroll
  for (int k = 0; k < 4; ++k) acc[k] *= invl;

  // BN partials: per (wave, row il) sum over the 16 lanes (x4 regs) sharing il
  float s1 = acc[0] + acc[1] + acc[2] + acc[3];
  float s2 = acc[0]*acc[0] + acc[1]*acc[1] + acc[2]*acc[2] + acc[3]*acc[3];
#pragma unroll
  for (int s = 4; s < 64; s <<= 1) { s1 += __shfl_xor(s1, s); s2 += __shfl_xor(s2, s); }
  if (lane < 4) { part[w][lane][0] = s1; part[w][lane][1] = s2; }
  __syncthreads();

  // total over the 4 batches (waves sharing ih): 256 values per node
  float tot1 = 0.f, tot2 = 0.f;
#pragma unroll
  for (int bb = 0; bb < 4; ++bb) {
    tot1 += part[bb * 2 + ih][il][0];
    tot2 += part[bb * 2 + ih][il][1];
  }
  float mean = tot1 * (1.0f / 256.0f);
  float var  = tot2 * (1.0f / 256.0f) - mean * mean;
  int gi = gi0 + il;
  float sc = gamma[gi] * rsqrtf(var + BN_EPS);
  float bt = beta[gi];

  const float4 hv = *(const float4*)(h + ((size_t)b * NN + gi) * FF + fb);
  float o[4];
  o[0] = sc * (acc[0] - mean) + bt + hv.x;
  o[1] = sc * (acc[1] - mean) + bt + hv.y;
  o[2] = sc * (acc[2] - mean) + bt + hv.z;
  o[3] = sc * (acc[3] - mean) + bt + hv.w;
#pragma unroll
  for (int k = 0; k < 4; ++k) o[k] = o[k] > 0.f ? o[k] : __expf(o[k]) - 1.f;
  float4 ov = make_float4(o[0], o[1], o[2], o[3]);
  *(float4*)(out + ((size_t)b * NN + gi) * FF + fb) = ov;
}

// ---------------------------------------------------------------------------
extern "C" void kernel_launch(void* const* d_in, const int* in_sizes, int n_in,
                              void* d_out, int out_size, void* d_ws, size_t ws_size,
                              hipStream_t stream) {
  (void)in_sizes; (void)n_in; (void)out_size; (void)ws_size;
  const float* h     = (const float*)d_in[0];
  const int*   adj   = (const int*)d_in[1];
  const float* W     = (const float*)d_in[2];
  const float* a     = (const float*)d_in[3];
  const float* gamma = (const float*)d_in[4];
  const float* beta  = (const float*)d_in[5];
  float* out = (float*)d_out;

  float* ws  = (float*)d_ws;
  float* Wh  = ws;                         // B*N*F   = 1048576 floats
  float* Wh1 = ws + 1048576;               // B*N     = 16384 floats
  float* Wh2 = ws + 1048576 + 16384;       // B*N     = 16384 floats

  k_wh<<<(BB * NN) / 8, 256, 0, stream>>>(h, W, a, Wh, Wh1, Wh2);
  k_gat<<<NN / 8, 512, 0, stream>>>(h, adj, gamma, beta, Wh, Wh1, Wh2, out);
}

// Round 2
// 100.532 us; speedup vs baseline: 5.1452x; 5.1452x over previous
//
#include <hip/hip_runtime.h>
#include <hip/hip_bf16.h>
#include <math.h>

#define NN 4096
#define BB 4
// (1/64) * log2(e)  -- folds 1/sqrt(N) and exp->exp2 conversion
#define SCL 0.022542110013890054f
#define LOG2E 1.4426950408889634f

typedef __attribute__((ext_vector_type(8))) short bf16x8;
typedef __attribute__((ext_vector_type(4))) float f32x4;

__device__ __forceinline__ float exp2_fast(float x) {
  float r; asm("v_exp_f32 %0, %1" : "=v"(r) : "v"(x)); return r;
}

// pack two f32 -> two bf16 (RTNE) in one u32 (low = first arg)
__device__ __forceinline__ unsigned pack2(float lo, float hi) {
  __hip_bfloat16 b0 = __float2bfloat16(lo), b1 = __float2bfloat16(hi);
  unsigned short u0 = *(unsigned short*)&b0;
  unsigned short u1 = *(unsigned short*)&b1;
  return (unsigned)u0 | ((unsigned)u1 << 16);
}

// ---------------------------------------------------------------------------
// Kernel 1: Wh = h@W ; emit WhT bf16 [B][64][4096], Wh1s/Wh2s = (Wh@a)*SCL.
// 8 rows (same batch) per 256-thread block; LDS transpose for WhT stores.
// ---------------------------------------------------------------------------
__global__ __launch_bounds__(256)
void k_wh(const float* __restrict__ h, const float* __restrict__ W,
          const float* __restrict__ a, unsigned short* __restrict__ WhT,
          float* __restrict__ Wh1s, float* __restrict__ Wh2s) {
  __shared__ float sW[4096];
  __shared__ unsigned short T[64][8];   // [f][row-local] bf16
  const int t = threadIdx.x;
#pragma unroll
  for (int i = 0; i < 16; ++i) sW[i * 256 + t] = W[i * 256 + t];
  __syncthreads();
  const int wv = t >> 6, lane = t & 63;
  const float a1 = a[lane], a2 = a[64 + lane];
  const int row0 = blockIdx.x * 8;                 // 8 rows, same batch (4096%8==0)
  for (int r = 0; r < 2; ++r) {
    const int row = row0 + wv * 2 + r;
    const float* hr = h + (size_t)row * 64;
    float acc = 0.f;
#pragma unroll
    for (int k = 0; k < 64; ++k) acc = fmaf(hr[k], sW[k * 64 + lane], acc);
    __hip_bfloat16 bv = __float2bfloat16(acc);
    T[lane][wv * 2 + r] = *(unsigned short*)&bv;
    float r1 = acc * a1, r2 = acc * a2;
#pragma unroll
    for (int sft = 32; sft; sft >>= 1) { r1 += __shfl_xor(r1, sft); r2 += __shfl_xor(r2, sft); }
    if (lane == 0) { Wh1s[row] = r1 * SCL; Wh2s[row] = r2 * SCL; }
  }
  __syncthreads();
  const int f = t >> 2, jp = t & 3;
  const int bidx = row0 >> 12, n0 = row0 & 4095;
  unsigned v = *(unsigned*)&T[f][jp * 2];
  *(unsigned*)(WhT + (((size_t)(bidx * 64 + f)) << 12) + n0 + jp * 2) = v;
}

// ---------------------------------------------------------------------------
// Kernel 2: fused masked-softmax attention (MFMA PV) + BN + residual + ELU.
// 1024 thr = 16 waves: wave (b = w>>2, s = w&3); all waves share 16 node rows
// i0..i0+15; s K-splits j into 32-wide windows. Main loop is barrier-free.
// Operand swap: D[f, i] = sum_j WhT[f,j] * P^T[j,i], so P is read from LDS as
// a contiguous b128 B-fragment and WhT A-frags come straight from global.
// ---------------------------------------------------------------------------
__global__ __launch_bounds__(1024, 4)
void k_gat(const float* __restrict__ h, const int* __restrict__ adj,
           const float* __restrict__ gamma, const float* __restrict__ beta,
           const unsigned short* __restrict__ WhT,
           const float* __restrict__ Wh1s, const float* __restrict__ Wh2s,
           float* __restrict__ out) {
  __shared__ unsigned short Ps[16][16][32];  // [wave][i][j-local] bf16, 16 KB
  __shared__ float hp[4][16][64];            // h' partials [b][i][f], 16 KB
  __shared__ float ls2[4][4][16];            // denom partials [s][b][i]
  __shared__ float bn2[4][16][2];            // BN partials [b][i][{s1,s2}]

  const int t = threadIdx.x;
  const int w = t >> 6, lane = t & 63;
  const int b = w >> 2, s = w & 3;
  const int i0 = blockIdx.x * 16;
  const int jp = lane & 15;   // score: j-pair idx | mfma: i (N-dim col)
  const int rg = lane >> 4;   // score: row group  | mfma: k-group

  const float4 w1v = *(const float4*)(Wh1s + b * NN + i0 + rg * 4);
  float w1c[4] = {w1v.x, w1v.y, w1v.z, w1v.w};
  const float2* __restrict__ w2p = (const float2*)(Wh2s + b * NN) + jp;
  const int2* __restrict__ ar0 = (const int2*)(adj + (size_t)(i0 + rg * 4 + 0) * NN) + jp;
  const int2* __restrict__ ar1 = (const int2*)(adj + (size_t)(i0 + rg * 4 + 1) * NN) + jp;
  const int2* __restrict__ ar2 = (const int2*)(adj + (size_t)(i0 + rg * 4 + 2) * NN) + jp;
  const int2* __restrict__ ar3 = (const int2*)(adj + (size_t)(i0 + rg * 4 + 3) * NN) + jp;
  const unsigned short* __restrict__ abase =
      WhT + (((size_t)(b * 64 + jp)) << 12) + rg * 8;  // row f=jp, k-group rg
  const int soff = s * 16;

  f32x4 acc[4];
#pragma unroll
  for (int ft = 0; ft < 4; ++ft) acc[ft] = (f32x4){0.f, 0.f, 0.f, 0.f};
  float lsum[4] = {0.f, 0.f, 0.f, 0.f};

  for (int jt = 0; jt < 32; ++jt) {
    const int j0 = jt * 128 + s * 32;   // element offset of this wave's window
    const int ji = jt * 64 + soff;      // int2/float2 index of window
    // issue all independent loads first (latency hides under score VALU)
    bf16x8 af[4];
#pragma unroll
    for (int ft = 0; ft < 4; ++ft)
      af[ft] = *(const bf16x8*)(abase + (ft << 16) + j0);
    const float2 w2 = w2p[ji];
    int2 avv[4];
    avv[0] = ar0[ji]; avv[1] = ar1[ji]; avv[2] = ar2[ji]; avv[3] = ar3[ji];

    // scores: 4 rows x 2 j per lane -> LDS bf16
#pragma unroll
    for (int r = 0; r < 4; ++r) {
      float y0 = w1c[r] + w2.x, y1 = w1c[r] + w2.y;
      float t0 = fmaxf(y0, 0.2f * y0), t1 = fmaxf(y1, 0.2f * y1);  // LeakyReLU
      t0 = avv[r].x ? t0 : -1e30f;
      t1 = avv[r].y ? t1 : -1e30f;
      float p0 = exp2_fast(t0), p1 = exp2_fast(t1);                // masked -> 0
      lsum[r] += p0 + p1;
      *(unsigned*)&Ps[w][rg * 4 + r][jp * 2] = pack2(p0, p1);
    }
    // B-frag: lane holds P^T[k = rg*8+e][i = jp]
    bf16x8 bfr = *(const bf16x8*)&Ps[w][jp][rg * 8];
#pragma unroll
    for (int ft = 0; ft < 4; ++ft)
      acc[ft] = __builtin_amdgcn_mfma_f32_16x16x32_bf16(af[ft], bfr, acc[ft], 0, 0, 0);
  }

  // denom: reduce over the 16 jp lanes
#pragma unroll
  for (int r = 0; r < 4; ++r) {
    float v = lsum[r];
#pragma unroll
    for (int m = 1; m < 16; m <<= 1) v += __shfl_xor(v, m);
    lsum[r] = v;
  }
  if (jp == 0)
    *(f32x4*)&ls2[s][b][rg * 4] = (f32x4){lsum[0], lsum[1], lsum[2], lsum[3]};
  __syncthreads();

  // combine h' partials across s (sequential, disjoint [b] regions per step)
  if (s == 3) {
#pragma unroll
    for (int ft = 0; ft < 4; ++ft)
      *(f32x4*)&hp[b][jp][ft * 16 + rg * 4] = acc[ft];
  }
  __syncthreads();
  if (s == 2) {
#pragma unroll
    for (int ft = 0; ft < 4; ++ft) {
      f32x4 tv = *(f32x4*)&hp[b][jp][ft * 16 + rg * 4];
      *(f32x4*)&hp[b][jp][ft * 16 + rg * 4] = tv + acc[ft];
    }
  }
  __syncthreads();
  if (s == 1) {
#pragma unroll
    for (int ft = 0; ft < 4; ++ft) {
      f32x4 tv = *(f32x4*)&hp[b][jp][ft * 16 + rg * 4];
      *(f32x4*)&hp[b][jp][ft * 16 + rg * 4] = tv + acc[ft];
    }
  }
  __syncthreads();

  float vv[4][4];
  if (s == 0) {
    float ltot = ls2[0][b][jp] + ls2[1][b][jp] + ls2[2][b][jp] + ls2[3][b][jp];
    float invl = 1.f / ltot;
    float s1 = 0.f, s2 = 0.f;
#pragma unroll
    for (int ft = 0; ft < 4; ++ft) {
      f32x4 tv = *(f32x4*)&hp[b][jp][ft * 16 + rg * 4];
#pragma unroll
      for (int r = 0; r < 4; ++r) {
        float x = (acc[ft][r] + tv[r]) * invl;   // normalized h'[f, i=jp]
        vv[ft][r] = x;
        s1 += x; s2 += x * x;
      }
    }
    s1 += __shfl_xor(s1, 16); s1 += __shfl_xor(s1, 32);
    s2 += __shfl_xor(s2, 16); s2 += __shfl_xor(s2, 32);
    if (rg == 0) { bn2[b][jp][0] = s1; bn2[b][jp][1] = s2; }
  }
  __syncthreads();
  if (s == 0) {
    float t1 = bn2[0][jp][0] + bn2[1][jp][0] + bn2[2][jp][0] + bn2[3][jp][0];
    float t2 = bn2[0][jp][1] + bn2[1][jp][1] + bn2[2][jp][1] + bn2[3][jp][1];
    float mean = t1 * (1.f / 256.f);
    float var  = t2 * (1.f / 256.f) - mean * mean;
    float sc = gamma[i0 + jp] * rsqrtf(var + 1e-5f);
    float bt = beta[i0 + jp];
    const float* hrow = h + ((size_t)(b * NN + i0 + jp)) * 64;
    float* orow = out + ((size_t)(b * NN + i0 + jp)) * 64;
#pragma unroll
    for (int ft = 0; ft < 4; ++ft) {
      const int fo = ft * 16 + rg * 4;
      float4 hv = *(const float4*)(hrow + fo);
      float o0 = sc * (vv[ft][0] - mean) + bt + hv.x;
      float o1 = sc * (vv[ft][1] - mean) + bt + hv.y;
      float o2 = sc * (vv[ft][2] - mean) + bt + hv.z;
      float o3 = sc * (vv[ft][3] - mean) + bt + hv.w;
      o0 = o0 > 0.f ? o0 : exp2_fast(o0 * LOG2E) - 1.f;
      o1 = o1 > 0.f ? o1 : exp2_fast(o1 * LOG2E) - 1.f;
      o2 = o2 > 0.f ? o2 : exp2_fast(o2 * LOG2E) - 1.f;
      o3 = o3 > 0.f ? o3 : exp2_fast(o3 * LOG2E) - 1.f;
      *(float4*)(orow + fo) = make_float4(o0, o1, o2, o3);
    }
  }
}

// ---------------------------------------------------------------------------
extern "C" void kernel_launch(void* const* d_in, const int* in_sizes, int n_in,
                              void* d_out, int out_size, void* d_ws, size_t ws_size,
                              hipStream_t stream) {
  (void)in_sizes; (void)n_in; (void)out_size; (void)ws_size;
  const float* h     = (const float*)d_in[0];
  const int*   adj   = (const int*)d_in[1];
  const float* W     = (const float*)d_in[2];
  const float* a     = (const float*)d_in[3];
  const float* gamma = (const float*)d_in[4];
  const float* beta  = (const float*)d_in[5];
  float* out = (float*)d_out;

  unsigned short* WhT = (unsigned short*)d_ws;                 // B*64*4096 bf16 = 2 MB
  float* Wh1s = (float*)((char*)d_ws + (size_t)BB * 64 * NN * 2);
  float* Wh2s = Wh1s + BB * NN;

  k_wh<<<(BB * NN) / 8, 256, 0, stream>>>(h, W, a, WhT, Wh1s, Wh2s);
  k_gat<<<NN / 16, 1024, 0, stream>>>(h, adj, gamma, beta, WhT, Wh1s, Wh2s, out);
}